// Round 1
// baseline (1361.526 us; speedup 1.0000x reference)
//
#include <hip/hip_runtime.h>
#include <hip/hip_bf16.h>
#include <math.h>

#define T_TOK 4096
#define D_DIM 1024
#define I_DIM 4096
#define E_EXP 8

typedef __attribute__((ext_vector_type(8))) short bf16x8;
typedef __attribute__((ext_vector_type(4))) float f32x4;

__device__ __forceinline__ unsigned short f2bf(float x) {
    unsigned int u = __float_as_uint(x);
    u += 0x7fffu + ((u >> 16) & 1u);   // RNE
    return (unsigned short)(u >> 16);
}

// ---------------- gate: logits (fp32 exact), softmax, top-2, weights ----------------
__global__ void gate_kernel(const float* __restrict__ h, const float* __restrict__ gw,
                            int* __restrict__ counts, int* __restrict__ sel,
                            float* __restrict__ wgt) {
    int t = blockIdx.x;
    int tid = threadIdx.x;
    float acc[E_EXP];
#pragma unroll
    for (int e = 0; e < E_EXP; e++) acc[e] = 0.f;
    const float* hr = h + (size_t)t * D_DIM;
    for (int d = tid; d < D_DIM; d += 256) {
        float hv = hr[d];
#pragma unroll
        for (int e = 0; e < E_EXP; e++) acc[e] += hv * gw[e * D_DIM + d];
    }
#pragma unroll
    for (int e = 0; e < E_EXP; e++)
        for (int off = 32; off > 0; off >>= 1) acc[e] += __shfl_down(acc[e], off, 64);
    __shared__ float red[4][E_EXP];
    int wave = tid >> 6, lane = tid & 63;
    if (lane == 0) {
#pragma unroll
        for (int e = 0; e < E_EXP; e++) red[wave][e] = acc[e];
    }
    __syncthreads();
    if (tid == 0) {
        float lg[E_EXP];
#pragma unroll
        for (int e = 0; e < E_EXP; e++) lg[e] = red[0][e] + red[1][e] + red[2][e] + red[3][e];
        float mx = lg[0];
#pragma unroll
        for (int e = 1; e < E_EXP; e++) mx = fmaxf(mx, lg[e]);
        float p[E_EXP];
#pragma unroll
        for (int e = 0; e < E_EXP; e++) p[e] = expf(lg[e] - mx);
        int i0 = 0; float b0 = p[0];
#pragma unroll
        for (int e = 1; e < E_EXP; e++) if (p[e] > b0) { b0 = p[e]; i0 = e; }
        int i1 = -1; float b1v = -1.f;
#pragma unroll
        for (int e = 0; e < E_EXP; e++) if (e != i0 && p[e] > b1v) { b1v = p[e]; i1 = e; }
        float den = b0 + b1v;
        sel[2 * t] = i0; sel[2 * t + 1] = i1;
        wgt[2 * t] = b0 / den; wgt[2 * t + 1] = b1v / den;
        atomicAdd(&counts[i0], 1);
        atomicAdd(&counts[i1], 1);
    }
}

// ---------------- offsets + cursors + aux loss ----------------
__global__ void offsets_kernel(const int* __restrict__ counts, int* __restrict__ offs,
                               int* __restrict__ cursors, float* __restrict__ aux_out) {
    if (blockIdx.x == 0 && threadIdx.x == 0) {
        int off = 0; float aux = 0.f;
        for (int e = 0; e < E_EXP; e++) {
            offs[e] = off; off += counts[e]; cursors[e] = 0;
            float u = (float)counts[e] / (float)T_TOK;
            float d = u - 1.0f / (float)E_EXP;
            aux += d * d;
        }
        aux_out[0] = aux / (float)E_EXP;
    }
}

// ---------------- scatter tokens into per-expert segments ----------------
__global__ void scatter_kernel(const int* __restrict__ sel, const float* __restrict__ wgt,
                               const int* __restrict__ offs, int* __restrict__ cursors,
                               int* __restrict__ tok_list, float* __restrict__ tok_w,
                               int* __restrict__ slot_of) {
    int t = blockIdx.x * 256 + threadIdx.x;
    if (t >= T_TOK) return;
#pragma unroll
    for (int k = 0; k < 2; k++) {
        int e = sel[2 * t + k];
        int pos = atomicAdd(&cursors[e], 1);
        int idx = offs[e] + pos;
        tok_list[idx] = t;
        tok_w[idx] = wgt[2 * t + k];
        slot_of[2 * t + k] = idx;
    }
}

// ---------------- H fp32 -> bf16 ----------------
__global__ void cvtH_kernel(const float* __restrict__ src, unsigned short* __restrict__ dst) {
    size_t i = ((size_t)blockIdx.x * 256 + threadIdx.x) * 8;
    float4 a = *(const float4*)(src + i);
    float4 b = *(const float4*)(src + i + 4);
    union { unsigned short u[8]; uint4 v; } o;
    o.u[0] = f2bf(a.x); o.u[1] = f2bf(a.y); o.u[2] = f2bf(a.z); o.u[3] = f2bf(a.w);
    o.u[4] = f2bf(b.x); o.u[5] = f2bf(b.y); o.u[6] = f2bf(b.z); o.u[7] = f2bf(b.w);
    *(uint4*)(dst + i) = o.v;
}

// ---------------- weight transpose + fp32->bf16: (E,R,C) -> (E,C,R) ----------------
__global__ void transpose_cvt_kernel(const float* __restrict__ src, unsigned short* __restrict__ dst,
                                     int R, int C) {
    __shared__ float tile[32][33];
    int e = blockIdx.z;
    const float* s = src + (size_t)e * R * C;
    unsigned short* d = dst + (size_t)e * R * C;
    int c0 = blockIdx.x * 32, r0 = blockIdx.y * 32;
    int tx = threadIdx.x, ty = threadIdx.y;
#pragma unroll
    for (int j = 0; j < 4; j++)
        tile[ty + 8 * j][tx] = s[(size_t)(r0 + ty + 8 * j) * C + c0 + tx];
    __syncthreads();
#pragma unroll
    for (int j = 0; j < 4; j++)
        d[(size_t)(c0 + ty + 8 * j) * R + r0 + tx] = f2bf(tile[tx][ty + 8 * j]);
}

// ---------------- grouped GEMM, 128x128 tile, mfma_f32_16x16x32_bf16 ----------------
// MODE 0: mid = gelu(gather(Hbf) @ W1t^T + b1)       -> bf16 mid (2T x I)
// MODE 1: slotbuf = tok_w * (mid @ W2t^T + b2)       -> fp32 slotbuf (2T x D)
template <int MODE>
__launch_bounds__(256)
__global__ void moe_gemm_kernel(const unsigned short* __restrict__ Abase,
                                const unsigned short* __restrict__ Bt,
                                const float* __restrict__ bias,
                                const int* __restrict__ counts, const int* __restrict__ offs,
                                const int* __restrict__ tok_list, const float* __restrict__ tok_w,
                                unsigned short* __restrict__ midout, float* __restrict__ slotbuf) {
    constexpr int K = (MODE == 0) ? D_DIM : I_DIM;
    constexpr int N = (MODE == 0) ? I_DIM : D_DIM;
    const int e = blockIdx.z;
    const int Ne = counts[e];
    const int m0 = blockIdx.x * 128;
    if (m0 >= Ne) return;
    const int n0 = blockIdx.y * 128;
    const int seg = offs[e];

    __shared__ __align__(16) unsigned short lA[128 * 40];
    __shared__ __align__(16) unsigned short lB[128 * 40];

    const int tid = threadIdx.x;
    const int lane = tid & 63;
    const int wave = tid >> 6;
    const int wm = (wave >> 1) * 64;
    const int wn = (wave & 1) * 64;
    const int quad = lane >> 4;
    const int l15 = lane & 15;

    // staging: 512 chunks of 8 bf16; chunk q -> row q>>2, seg q&3
    const int r0_ = tid >> 2, s0_ = tid & 3;
    const int r1_ = r0_ + 64;

    size_t arow0, arow1;
    {
        int mr0 = m0 + r0_, mr1 = m0 + r1_;
        if (MODE == 0) {
            int t0 = tok_list[seg + (mr0 < Ne ? mr0 : 0)];
            int t1 = tok_list[seg + (mr1 < Ne ? mr1 : 0)];
            arow0 = (size_t)t0 * K;
            arow1 = (size_t)t1 * K;
        } else {
            arow0 = (size_t)(seg + (mr0 < Ne ? mr0 : 0)) * K;
            arow1 = (size_t)(seg + (mr1 < Ne ? mr1 : 0)) * K;
        }
    }
    const unsigned short* Bte = Bt + (size_t)e * N * K;
    const size_t brow0 = (size_t)(n0 + r0_) * K;
    const size_t brow1 = (size_t)(n0 + r1_) * K;

    f32x4 acc[4][4];
#pragma unroll
    for (int i = 0; i < 4; i++)
#pragma unroll
        for (int j = 0; j < 4; j++) acc[i][j] = (f32x4){0.f, 0.f, 0.f, 0.f};

    for (int k0 = 0; k0 < K; k0 += 32) {
        *(uint4*)&lA[r0_ * 40 + s0_ * 8] = *(const uint4*)&Abase[arow0 + k0 + s0_ * 8];
        *(uint4*)&lA[r1_ * 40 + s0_ * 8] = *(const uint4*)&Abase[arow1 + k0 + s0_ * 8];
        *(uint4*)&lB[r0_ * 40 + s0_ * 8] = *(const uint4*)&Bte[brow0 + k0 + s0_ * 8];
        *(uint4*)&lB[r1_ * 40 + s0_ * 8] = *(const uint4*)&Bte[brow1 + k0 + s0_ * 8];
        __syncthreads();
        bf16x8 af[4], bfr[4];
#pragma unroll
        for (int i = 0; i < 4; i++)
            af[i] = *(const bf16x8*)&lA[(wm + i * 16 + l15) * 40 + quad * 8];
#pragma unroll
        for (int j = 0; j < 4; j++)
            bfr[j] = *(const bf16x8*)&lB[(wn + j * 16 + l15) * 40 + quad * 8];
#pragma unroll
        for (int i = 0; i < 4; i++)
#pragma unroll
            for (int j = 0; j < 4; j++)
                acc[i][j] = __builtin_amdgcn_mfma_f32_16x16x32_bf16(af[i], bfr[j], acc[i][j], 0, 0, 0);
        __syncthreads();
    }

    const float* be = bias + (size_t)e * N;
#pragma unroll
    for (int i = 0; i < 4; i++) {
        int mbase = m0 + wm + i * 16 + quad * 4;
#pragma unroll
        for (int j = 0; j < 4; j++) {
            int n = n0 + wn + j * 16 + l15;
            float bv = be[n];
#pragma unroll
            for (int r = 0; r < 4; r++) {
                int m = mbase + r;
                if (m < Ne) {
                    float v = acc[i][j][r] + bv;
                    if (MODE == 0) {
                        v = 0.5f * v * (1.0f + erff(v * 0.70710678118654752f));
                        midout[(size_t)(seg + m) * N + n] = f2bf(v);
                    } else {
                        slotbuf[(size_t)(seg + m) * N + n] = tok_w[seg + m] * v;
                    }
                }
            }
        }
    }
}

// ---------------- residual + mask + LayerNorm ----------------
__global__ void ln_kernel(const float* __restrict__ hs, const float* __restrict__ mask,
                          const float* __restrict__ slotbuf, const int* __restrict__ slot_of,
                          const float* __restrict__ gamma, const float* __restrict__ beta,
                          float* __restrict__ outp) {
    int t = blockIdx.x, tid = threadIdx.x;
    int s0 = slot_of[2 * t], s1 = slot_of[2 * t + 1];
    float mk = mask[t];
    const float4* hr = (const float4*)(hs + (size_t)t * D_DIM);
    const float4* p0 = (const float4*)(slotbuf + (size_t)s0 * D_DIM);
    const float4* p1 = (const float4*)(slotbuf + (size_t)s1 * D_DIM);
    float4 hv = hr[tid], a = p0[tid], b = p1[tid];
    float x0 = hv.x + mk * (a.x + b.x);
    float x1 = hv.y + mk * (a.y + b.y);
    float x2 = hv.z + mk * (a.z + b.z);
    float x3 = hv.w + mk * (a.w + b.w);
    float sum = x0 + x1 + x2 + x3;
    float sq = x0 * x0 + x1 * x1 + x2 * x2 + x3 * x3;
    for (int off = 32; off > 0; off >>= 1) {
        sum += __shfl_down(sum, off, 64);
        sq += __shfl_down(sq, off, 64);
    }
    __shared__ float rsum[4], rsq[4];
    __shared__ float mu_s, rstd_s;
    int wave = tid >> 6, lane = tid & 63;
    if (lane == 0) { rsum[wave] = sum; rsq[wave] = sq; }
    __syncthreads();
    if (tid == 0) {
        float s = rsum[0] + rsum[1] + rsum[2] + rsum[3];
        float q = rsq[0] + rsq[1] + rsq[2] + rsq[3];
        float mu = s / (float)D_DIM;
        float var = q / (float)D_DIM - mu * mu;
        mu_s = mu; rstd_s = rsqrtf(var + 1e-5f);
    }
    __syncthreads();
    float mu = mu_s, rstd = rstd_s;
    const float4* g4 = (const float4*)gamma;
    const float4* b4 = (const float4*)beta;
    float4 g = g4[tid], bb = b4[tid];
    float4 o;
    o.x = (x0 - mu) * rstd * g.x + bb.x;
    o.y = (x1 - mu) * rstd * g.y + bb.y;
    o.z = (x2 - mu) * rstd * g.z + bb.z;
    o.w = (x3 - mu) * rstd * g.w + bb.w;
    ((float4*)(outp + (size_t)t * D_DIM))[tid] = o;
}

extern "C" void kernel_launch(void* const* d_in, const int* in_sizes, int n_in,
                              void* d_out, int out_size, void* d_ws, size_t ws_size,
                              hipStream_t stream) {
    const float* hs    = (const float*)d_in[0];
    const float* mask  = (const float*)d_in[1];
    const float* gw    = (const float*)d_in[2];
    const float* w1    = (const float*)d_in[3];
    const float* b1    = (const float*)d_in[4];
    const float* w2    = (const float*)d_in[5];
    const float* b2    = (const float*)d_in[6];
    const float* gamma = (const float*)d_in[7];
    const float* beta  = (const float*)d_in[8];
    float* out = (float*)d_out;

    // workspace layout (233 MiB total)
    char* ws = (char*)d_ws;
    int*   counts   = (int*)(ws + 0);
    int*   cursors  = (int*)(ws + 64);
    int*   offs     = (int*)(ws + 128);
    int*   sel      = (int*)(ws + 4096);
    float* wgt      = (float*)(ws + 4096 + 1 * 32768);
    int*   slot_of  = (int*)(ws + 4096 + 2 * 32768);
    int*   tok_list = (int*)(ws + 4096 + 3 * 32768);
    float* tok_w    = (float*)(ws + 4096 + 4 * 32768);
    unsigned short* Hbf = (unsigned short*)(ws + (1ull << 20));    //  8 MiB
    unsigned short* W1t = (unsigned short*)(ws + (9ull << 20));    // 64 MiB  (E,I,D) bf16
    unsigned short* W2t = (unsigned short*)(ws + (73ull << 20));   // 64 MiB  (E,D,I) bf16
    unsigned short* mid = (unsigned short*)(ws + (137ull << 20));  // 64 MiB  (2T,I) bf16
    float* slotbuf      = (float*)(ws + (201ull << 20));           // 32 MiB  (2T,D) f32

    hipMemsetAsync(counts, 0, 64, stream);
    gate_kernel<<<T_TOK, 256, 0, stream>>>(hs, gw, counts, sel, wgt);
    offsets_kernel<<<1, 64, 0, stream>>>(counts, offs, cursors, out + (size_t)T_TOK * D_DIM);
    scatter_kernel<<<T_TOK / 256, 256, 0, stream>>>(sel, wgt, offs, cursors, tok_list, tok_w, slot_of);
    cvtH_kernel<<<(T_TOK * D_DIM / 8) / 256, 256, 0, stream>>>(hs, Hbf);
    transpose_cvt_kernel<<<dim3(I_DIM / 32, D_DIM / 32, E_EXP), dim3(32, 8), 0, stream>>>(w1, W1t, D_DIM, I_DIM);
    transpose_cvt_kernel<<<dim3(D_DIM / 32, I_DIM / 32, E_EXP), dim3(32, 8), 0, stream>>>(w2, W2t, I_DIM, D_DIM);
    moe_gemm_kernel<0><<<dim3(T_TOK / 128, I_DIM / 128, E_EXP), 256, 0, stream>>>(
        Hbf, W1t, b1, counts, offs, tok_list, tok_w, mid, nullptr);
    moe_gemm_kernel<1><<<dim3(T_TOK / 128, D_DIM / 128, E_EXP), 256, 0, stream>>>(
        mid, W2t, b2, counts, offs, tok_list, tok_w, nullptr, slotbuf);
    ln_kernel<<<T_TOK, 256, 0, stream>>>(hs, mask, slotbuf, slot_of, gamma, beta, out);
}

// Round 2
// 764.343 us; speedup vs baseline: 1.7813x; 1.7813x over previous
//
#include <hip/hip_runtime.h>
#include <hip/hip_bf16.h>
#include <math.h>

#define T_TOK 4096
#define D_DIM 1024
#define I_DIM 4096
#define E_EXP 8
#define MAX_TILES 72

typedef __attribute__((ext_vector_type(8))) short bf16x8;
typedef __attribute__((ext_vector_type(4))) float f32x4;

__device__ __forceinline__ unsigned short f2bf(float x) {
    unsigned int u = __float_as_uint(x);
    u += 0x7fffu + ((u >> 16) & 1u);   // RNE
    return (unsigned short)(u >> 16);
}

// async global->LDS, 16B per lane; lds dest = wave-uniform base + lane*16
__device__ __forceinline__ void glds16(const unsigned short* g, unsigned short* l) {
    __builtin_amdgcn_global_load_lds(
        (const __attribute__((address_space(1))) unsigned int*)g,
        (__attribute__((address_space(3))) unsigned int*)(unsigned int)(unsigned long long)(void*)l,
        16, 0, 0);
}

// ---------------- gate: logits (fp32 exact), softmax, top-2, weights ----------------
__global__ void gate_kernel(const float* __restrict__ h, const float* __restrict__ gw,
                            int* __restrict__ counts, int* __restrict__ sel,
                            float* __restrict__ wgt) {
    int t = blockIdx.x;
    int tid = threadIdx.x;
    float acc[E_EXP];
#pragma unroll
    for (int e = 0; e < E_EXP; e++) acc[e] = 0.f;
    const float* hr = h + (size_t)t * D_DIM;
    for (int d = tid; d < D_DIM; d += 256) {
        float hv = hr[d];
#pragma unroll
        for (int e = 0; e < E_EXP; e++) acc[e] += hv * gw[e * D_DIM + d];
    }
#pragma unroll
    for (int e = 0; e < E_EXP; e++)
        for (int off = 32; off > 0; off >>= 1) acc[e] += __shfl_down(acc[e], off, 64);
    __shared__ float red[4][E_EXP];
    int wave = tid >> 6, lane = tid & 63;
    if (lane == 0) {
#pragma unroll
        for (int e = 0; e < E_EXP; e++) red[wave][e] = acc[e];
    }
    __syncthreads();
    if (tid == 0) {
        float lg[E_EXP];
#pragma unroll
        for (int e = 0; e < E_EXP; e++) lg[e] = red[0][e] + red[1][e] + red[2][e] + red[3][e];
        float mx = lg[0];
#pragma unroll
        for (int e = 1; e < E_EXP; e++) mx = fmaxf(mx, lg[e]);
        float p[E_EXP];
#pragma unroll
        for (int e = 0; e < E_EXP; e++) p[e] = expf(lg[e] - mx);
        int i0 = 0; float b0 = p[0];
#pragma unroll
        for (int e = 1; e < E_EXP; e++) if (p[e] > b0) { b0 = p[e]; i0 = e; }
        int i1 = -1; float b1v = -1.f;
#pragma unroll
        for (int e = 0; e < E_EXP; e++) if (e != i0 && p[e] > b1v) { b1v = p[e]; i1 = e; }
        float den = b0 + b1v;
        sel[2 * t] = i0; sel[2 * t + 1] = i1;
        wgt[2 * t] = b0 / den; wgt[2 * t + 1] = b1v / den;
        atomicAdd(&counts[i0], 1);
        atomicAdd(&counts[i1], 1);
    }
}

// ---------------- offsets + cursors + aux loss + compacted tile table ----------------
__global__ void offsets_kernel(const int* __restrict__ counts, int* __restrict__ offs,
                               int* __restrict__ cursors, float* __restrict__ aux_out,
                               int* __restrict__ tile_e, int* __restrict__ tile_m,
                               int* __restrict__ ntiles) {
    if (blockIdx.x == 0 && threadIdx.x == 0) {
        int off = 0; float aux = 0.f; int nt = 0;
        for (int e = 0; e < E_EXP; e++) {
            offs[e] = off; off += counts[e]; cursors[e] = 0;
            float u = (float)counts[e] / (float)T_TOK;
            float d = u - 1.0f / (float)E_EXP;
            aux += d * d;
            for (int m0 = 0; m0 < counts[e]; m0 += 128) {
                tile_e[nt] = e; tile_m[nt] = m0; nt++;
            }
        }
        ntiles[0] = nt;
        aux_out[0] = aux / (float)E_EXP;
    }
}

// ---------------- scatter tokens into per-expert segments ----------------
__global__ void scatter_kernel(const int* __restrict__ sel, const float* __restrict__ wgt,
                               const int* __restrict__ offs, int* __restrict__ cursors,
                               int* __restrict__ tok_list, float* __restrict__ tok_w,
                               int* __restrict__ slot_of) {
    int t = blockIdx.x * 256 + threadIdx.x;
    if (t >= T_TOK) return;
#pragma unroll
    for (int k = 0; k < 2; k++) {
        int e = sel[2 * t + k];
        int pos = atomicAdd(&cursors[e], 1);
        int idx = offs[e] + pos;
        tok_list[idx] = t;
        tok_w[idx] = wgt[2 * t + k];
        slot_of[2 * t + k] = idx;
    }
}

// ---------------- H fp32 -> bf16 ----------------
__global__ void cvtH_kernel(const float* __restrict__ src, unsigned short* __restrict__ dst) {
    size_t i = ((size_t)blockIdx.x * 256 + threadIdx.x) * 8;
    float4 a = *(const float4*)(src + i);
    float4 b = *(const float4*)(src + i + 4);
    union { unsigned short u[8]; uint4 v; } o;
    o.u[0] = f2bf(a.x); o.u[1] = f2bf(a.y); o.u[2] = f2bf(a.z); o.u[3] = f2bf(a.w);
    o.u[4] = f2bf(b.x); o.u[5] = f2bf(b.y); o.u[6] = f2bf(b.z); o.u[7] = f2bf(b.w);
    *(uint4*)(dst + i) = o.v;
}

// ---------------- weight transpose + fp32->bf16: (E,R,C) -> (E,C,R) ----------------
__global__ void transpose_cvt_kernel(const float* __restrict__ src, unsigned short* __restrict__ dst,
                                     int R, int C) {
    __shared__ float tile[32][33];
    int e = blockIdx.z;
    const float* s = src + (size_t)e * R * C;
    unsigned short* d = dst + (size_t)e * R * C;
    int c0 = blockIdx.x * 32, r0 = blockIdx.y * 32;
    int tx = threadIdx.x, ty = threadIdx.y;
#pragma unroll
    for (int j = 0; j < 4; j++)
        tile[ty + 8 * j][tx] = s[(size_t)(r0 + ty + 8 * j) * C + c0 + tx];
    __syncthreads();
#pragma unroll
    for (int j = 0; j < 4; j++)
        d[(size_t)(c0 + ty + 8 * j) * R + r0 + tx] = f2bf(tile[tx][ty + 8 * j]);
}

// ---------------- grouped GEMM, 128x128 tile, mfma_f32_16x16x32_bf16, glds staging ----------------
// MODE 0: mid = gelu(gather(Hbf) @ W1t^T + b1)       -> bf16 mid (2T x I)
// MODE 1: slotbuf = tok_w * (mid @ W2t^T + b2)       -> fp32 slotbuf (2T x D)
template <int MODE>
__launch_bounds__(256)
__global__ void moe_gemm_kernel(const unsigned short* __restrict__ Abase,
                                const unsigned short* __restrict__ Bt,
                                const float* __restrict__ bias,
                                const int* __restrict__ counts, const int* __restrict__ offs,
                                const int* __restrict__ tile_e, const int* __restrict__ tile_m,
                                const int* __restrict__ ntiles,
                                const int* __restrict__ tok_list, const float* __restrict__ tok_w,
                                unsigned short* __restrict__ midout, float* __restrict__ slotbuf) {
    constexpr int K = (MODE == 0) ? D_DIM : I_DIM;
    constexpr int N = (MODE == 0) ? I_DIM : D_DIM;
    const int tix = blockIdx.x;
    if (tix >= ntiles[0]) return;
    const int e = tile_e[tix];
    const int m0 = tile_m[tix];
    const int Ne = counts[e];
    const int n0 = blockIdx.y * 128;
    const int seg = offs[e];

    // unpadded: row stride 32 shorts (64 B) — required by glds lane-contiguous dest
    __shared__ __align__(16) unsigned short lA[128 * 32];
    __shared__ __align__(16) unsigned short lB[128 * 32];

    const int tid = threadIdx.x;
    const int lane = tid & 63;
    const int wave = tid >> 6;
    const int wm = (wave >> 1) * 64;
    const int wn = (wave & 1) * 64;
    const int quad = lane >> 4;
    const int l15 = lane & 15;

    // staging: wave w covers rows [w*32, w*32+32): two calls of 16 rows each.
    // lane i -> row base + (i>>2), 16B col segment (i&3)
    const int srow = wave * 32 + (lane >> 2);
    const int scol = (lane & 3) * 8;  // in shorts

    const unsigned short *pA0, *pA1;
    {
        int mr0 = m0 + srow, mr1 = mr0 + 16;
        size_t arow0, arow1;
        if (MODE == 0) {
            arow0 = (size_t)tok_list[seg + (mr0 < Ne ? mr0 : 0)] * K;
            arow1 = (size_t)tok_list[seg + (mr1 < Ne ? mr1 : 0)] * K;
        } else {
            arow0 = (size_t)(seg + (mr0 < Ne ? mr0 : 0)) * K;
            arow1 = (size_t)(seg + (mr1 < Ne ? mr1 : 0)) * K;
        }
        pA0 = Abase + arow0 + scol;
        pA1 = Abase + arow1 + scol;
    }
    const unsigned short* Bte = Bt + (size_t)e * N * K;
    const unsigned short* pB0 = Bte + (size_t)(n0 + srow) * K + scol;
    const unsigned short* pB1 = Bte + (size_t)(n0 + srow + 16) * K + scol;

    unsigned short* dA0 = lA + (wave * 32) * 32;
    unsigned short* dA1 = lA + (wave * 32 + 16) * 32;
    unsigned short* dB0 = lB + (wave * 32) * 32;
    unsigned short* dB1 = lB + (wave * 32 + 16) * 32;

    f32x4 acc[4][4];
#pragma unroll
    for (int i = 0; i < 4; i++)
#pragma unroll
        for (int j = 0; j < 4; j++) acc[i][j] = (f32x4){0.f, 0.f, 0.f, 0.f};

    for (int k0 = 0; k0 < K; k0 += 32) {
        glds16(pA0, dA0);
        glds16(pA1, dA1);
        glds16(pB0, dB0);
        glds16(pB1, dB1);
        pA0 += 32; pA1 += 32; pB0 += 32; pB1 += 32;
        __syncthreads();   // drains vmcnt(0): glds complete for whole block
        bf16x8 af[4], bfr[4];
#pragma unroll
        for (int i = 0; i < 4; i++)
            af[i] = *(const bf16x8*)&lA[(wm + i * 16 + l15) * 32 + quad * 8];
#pragma unroll
        for (int j = 0; j < 4; j++)
            bfr[j] = *(const bf16x8*)&lB[(wn + j * 16 + l15) * 32 + quad * 8];
#pragma unroll
        for (int i = 0; i < 4; i++)
#pragma unroll
            for (int j = 0; j < 4; j++)
                acc[i][j] = __builtin_amdgcn_mfma_f32_16x16x32_bf16(af[i], bfr[j], acc[i][j], 0, 0, 0);
        __syncthreads();
    }

    const float* be = bias + (size_t)e * N;
#pragma unroll
    for (int i = 0; i < 4; i++) {
        int mbase = m0 + wm + i * 16 + quad * 4;
#pragma unroll
        for (int j = 0; j < 4; j++) {
            int n = n0 + wn + j * 16 + l15;
            float bv = be[n];
#pragma unroll
            for (int r = 0; r < 4; r++) {
                int m = mbase + r;
                if (m < Ne) {
                    float v = acc[i][j][r] + bv;
                    if (MODE == 0) {
                        v = 0.5f * v * (1.0f + erff(v * 0.70710678118654752f));
                        midout[(size_t)(seg + m) * N + n] = f2bf(v);
                    } else {
                        slotbuf[(size_t)(seg + m) * N + n] = tok_w[seg + m] * v;
                    }
                }
            }
        }
    }
}

// ---------------- residual + mask + LayerNorm ----------------
__global__ void ln_kernel(const float* __restrict__ hs, const float* __restrict__ mask,
                          const float* __restrict__ slotbuf, const int* __restrict__ slot_of,
                          const float* __restrict__ gamma, const float* __restrict__ beta,
                          float* __restrict__ outp) {
    int t = blockIdx.x, tid = threadIdx.x;
    int s0 = slot_of[2 * t], s1 = slot_of[2 * t + 1];
    float mk = mask[t];
    const float4* hr = (const float4*)(hs + (size_t)t * D_DIM);
    const float4* p0 = (const float4*)(slotbuf + (size_t)s0 * D_DIM);
    const float4* p1 = (const float4*)(slotbuf + (size_t)s1 * D_DIM);
    float4 hv = hr[tid], a = p0[tid], b = p1[tid];
    float x0 = hv.x + mk * (a.x + b.x);
    float x1 = hv.y + mk * (a.y + b.y);
    float x2 = hv.z + mk * (a.z + b.z);
    float x3 = hv.w + mk * (a.w + b.w);
    float sum = x0 + x1 + x2 + x3;
    float sq = x0 * x0 + x1 * x1 + x2 * x2 + x3 * x3;
    for (int off = 32; off > 0; off >>= 1) {
        sum += __shfl_down(sum, off, 64);
        sq += __shfl_down(sq, off, 64);
    }
    __shared__ float rsum[4], rsq[4];
    __shared__ float mu_s, rstd_s;
    int wave = tid >> 6, lane = tid & 63;
    if (lane == 0) { rsum[wave] = sum; rsq[wave] = sq; }
    __syncthreads();
    if (tid == 0) {
        float s = rsum[0] + rsum[1] + rsum[2] + rsum[3];
        float q = rsq[0] + rsq[1] + rsq[2] + rsq[3];
        float mu = s / (float)D_DIM;
        float var = q / (float)D_DIM - mu * mu;
        mu_s = mu; rstd_s = rsqrtf(var + 1e-5f);
    }
    __syncthreads();
    float mu = mu_s, rstd = rstd_s;
    const float4* g4 = (const float4*)gamma;
    const float4* b4 = (const float4*)beta;
    float4 g = g4[tid], bb = b4[tid];
    float4 o;
    o.x = (x0 - mu) * rstd * g.x + bb.x;
    o.y = (x1 - mu) * rstd * g.y + bb.y;
    o.z = (x2 - mu) * rstd * g.z + bb.z;
    o.w = (x3 - mu) * rstd * g.w + bb.w;
    ((float4*)(outp + (size_t)t * D_DIM))[tid] = o;
}

extern "C" void kernel_launch(void* const* d_in, const int* in_sizes, int n_in,
                              void* d_out, int out_size, void* d_ws, size_t ws_size,
                              hipStream_t stream) {
    const float* hs    = (const float*)d_in[0];
    const float* mask  = (const float*)d_in[1];
    const float* gw    = (const float*)d_in[2];
    const float* w1    = (const float*)d_in[3];
    const float* b1    = (const float*)d_in[4];
    const float* w2    = (const float*)d_in[5];
    const float* b2    = (const float*)d_in[6];
    const float* gamma = (const float*)d_in[7];
    const float* beta  = (const float*)d_in[8];
    float* out = (float*)d_out;

    char* ws = (char*)d_ws;
    int*   counts   = (int*)(ws + 0);
    int*   cursors  = (int*)(ws + 64);
    int*   offs     = (int*)(ws + 128);
    int*   ntiles   = (int*)(ws + 256);
    int*   tile_e   = (int*)(ws + 512);
    int*   tile_m   = (int*)(ws + 1024);
    int*   sel      = (int*)(ws + 4096);
    float* wgt      = (float*)(ws + 4096 + 1 * 32768);
    int*   slot_of  = (int*)(ws + 4096 + 2 * 32768);
    int*   tok_list = (int*)(ws + 4096 + 3 * 32768);
    float* tok_w    = (float*)(ws + 4096 + 4 * 32768);
    unsigned short* Hbf = (unsigned short*)(ws + (1ull << 20));    //  8 MiB
    unsigned short* W1t = (unsigned short*)(ws + (9ull << 20));    // 64 MiB  (E,I,D) bf16
    unsigned short* W2t = (unsigned short*)(ws + (73ull << 20));   // 64 MiB  (E,D,I) bf16
    unsigned short* mid = (unsigned short*)(ws + (137ull << 20));  // 64 MiB  (2T,I) bf16
    float* slotbuf      = (float*)(ws + (201ull << 20));           // 32 MiB  (2T,D) f32

    hipMemsetAsync(counts, 0, 64, stream);
    gate_kernel<<<T_TOK, 256, 0, stream>>>(hs, gw, counts, sel, wgt);
    offsets_kernel<<<1, 64, 0, stream>>>(counts, offs, cursors, out + (size_t)T_TOK * D_DIM,
                                         tile_e, tile_m, ntiles);
    scatter_kernel<<<T_TOK / 256, 256, 0, stream>>>(sel, wgt, offs, cursors, tok_list, tok_w, slot_of);
    cvtH_kernel<<<(T_TOK * D_DIM / 8) / 256, 256, 0, stream>>>(hs, Hbf);
    transpose_cvt_kernel<<<dim3(I_DIM / 32, D_DIM / 32, E_EXP), dim3(32, 8), 0, stream>>>(w1, W1t, D_DIM, I_DIM);
    transpose_cvt_kernel<<<dim3(D_DIM / 32, I_DIM / 32, E_EXP), dim3(32, 8), 0, stream>>>(w2, W2t, I_DIM, D_DIM);
    moe_gemm_kernel<0><<<dim3(MAX_TILES, I_DIM / 128), 256, 0, stream>>>(
        Hbf, W1t, b1, counts, offs, tile_e, tile_m, ntiles, tok_list, tok_w, mid, nullptr);
    moe_gemm_kernel<1><<<dim3(MAX_TILES, D_DIM / 128), 256, 0, stream>>>(
        mid, W2t, b2, counts, offs, tile_e, tile_m, ntiles, tok_list, tok_w, nullptr, slotbuf);
    ln_kernel<<<T_TOK, 256, 0, stream>>>(hs, mask, slotbuf, slot_of, gamma, beta, out);
}